// Round 3
// baseline (53.798 us; speedup 1.0000x reference)
//
#include <hip/hip_runtime.h>
#include <hip/hip_bf16.h>
#include <math.h>

#define B   8
#define S   64
#define NL  128
#define NPRO 256
#define NN  384   // NL + NPRO
#define P   64
#define NGRP 8
#define EPSF 1e-6f

// ---------------------------------------------------------------------------
// Kernel 1: mean_len[b,s]
// ---------------------------------------------------------------------------
__global__ __launch_bounds__(64) void meanlen_kernel(
    const float* __restrict__ lig, const float* __restrict__ ligmask,
    const float* __restrict__ pro, const float* __restrict__ promask,
    float* __restrict__ meanlen)
{
    int blk = blockIdx.x;              // b*S + s
    int t = threadIdx.x;
    float suml = 0.f, cnt = 0.f;

    const float* lbase = lig + (size_t)blk * NL * 3;
    const float* lm    = ligmask + (size_t)blk * NL;
    for (int n = t; n < NL; n += 64) {
        float x = lbase[n*3+0], y = lbase[n*3+1], z = lbase[n*3+2];
        float mk = lm[n];
        suml += sqrtf(x*x + y*y + z*z) * mk;
        cnt  += mk;
    }
    const float* pbase = pro + (size_t)blk * NPRO * 3;
    const float* pm    = promask + (size_t)blk * NPRO;
    for (int n = t; n < NPRO; n += 64) {
        float x = pbase[n*3+0], y = pbase[n*3+1], z = pbase[n*3+2];
        float mk = pm[n];
        suml += sqrtf(x*x + y*y + z*z) * mk;
        cnt  += mk;
    }
    for (int off = 32; off > 0; off >>= 1) {
        suml += __shfl_down(suml, off);
        cnt  += __shfl_down(cnt,  off);
    }
    if (t == 0) meanlen[blk] = suml / cnt;
}

// ---------------------------------------------------------------------------
// Kernel 2: SoA projection planes
// projc[b,n,p] = sum_s coord[b,s,n,c] * sw[s]/(mean+eps)*mask * w[p,s]
// ---------------------------------------------------------------------------
__global__ __launch_bounds__(64) void proj_kernel(
    const float* __restrict__ lig, const float* __restrict__ pro,
    const float* __restrict__ ligmask, const float* __restrict__ promask,
    const float* __restrict__ ligw, const float* __restrict__ prow,
    const float* __restrict__ sw, const float* __restrict__ meanlen,
    float* __restrict__ projx, float* __restrict__ projy, float* __restrict__ projz)
{
    int blk = blockIdx.x;
    int b = blk / (NN / NGRP);
    int g = blk - b * (NN / NGRP);
    int nbase = g * NGRP;
    int t = threadIdx.x;
    bool isl = (nbase < NL);

    __shared__ float wl[64][65];           // wl[p][s], padded
    const float* w = isl ? ligw : prow;    // (P,S)
    for (int row = 0; row < 64; ++row) wl[row][t] = w[row * 64 + t];

    __shared__ float cs[NGRP][3][64];      // coords premultiplied by g-factor
    {
        int s = t;
        float gfac = sw[s] / (meanlen[b * S + s] + EPSF);
        for (int nn = 0; nn < NGRP; ++nn) {
            int n = nbase + nn;
            float mk, X, Y, Z;
            if (isl) {
                size_t base = ((size_t)b * S + s) * NL + n;
                mk = ligmask[base];
                X = lig[base*3+0]; Y = lig[base*3+1]; Z = lig[base*3+2];
            } else {
                size_t base = ((size_t)b * S + s) * NPRO + (n - NL);
                mk = promask[base];
                X = pro[base*3+0]; Y = pro[base*3+1]; Z = pro[base*3+2];
            }
            float gg = gfac * mk;
            cs[nn][0][s] = X * gg;
            cs[nn][1][s] = Y * gg;
            cs[nn][2][s] = Z * gg;
        }
    }
    __syncthreads();

    for (int nn = 0; nn < NGRP; ++nn) {
        float a0 = 0.f, a1 = 0.f, a2 = 0.f;
        #pragma unroll 8
        for (int s = 0; s < 64; ++s) {
            float wv = wl[t][s];
            a0 += cs[nn][0][s] * wv;
            a1 += cs[nn][1][s] * wv;
            a2 += cs[nn][2][s] * wv;
        }
        size_t base = ((size_t)b * NN + nbase + nn) * P;
        projx[base + t] = a0;
        projy[base + t] = a1;
        projz[base + t] = a2;
    }
}

// ---------------------------------------------------------------------------
// Kernel 3 (dominant): fused softmax + normalized-diff accumulation +
// attn^2 weights + output projection.
// grid = B*NL blocks, 512 threads = 8 waves.
// Thread: pg = lane&15 -> 4 consecutive p (float4); slice = wave*4 + (lane>>4)
// handles n in [slice*12, slice*12+12). Explicit 1-deep load pipeline.
// ---------------------------------------------------------------------------
#define PROC(C) { \
    float d0 = xix.C - xx.C, d1 = xiy.C - yy.C, d2 = xiz.C - zz.C; \
    float sq = fmaf(d0, d0, fmaf(d1, d1, d2 * d2)); \
    float inv; asm("v_rsq_f32 %0, %1" : "=v"(inv) : "v"(sq)); \
    inv = sq > 0.f ? inv : 0.f; \
    float xe = fmaf(mm.C, 1.44269504f, am); \
    float e; asm("v_exp_f32 %0, %1" : "=v"(e) : "v"(xe)); \
    S1.C += e; S2.C = fmaf(e, e, S2.C); \
    float ei = e * inv; \
    A0.C = fmaf(ei, d0, A0.C); \
    A1.C = fmaf(ei, d1, A1.C); \
    A2.C = fmaf(ei, d2, A2.C); }

#define RED(V) { V.x += __shfl_xor(V.x, off); V.y += __shfl_xor(V.y, off); \
                 V.z += __shfl_xor(V.z, off); V.w += __shfl_xor(V.w, off); }

__global__ __launch_bounds__(512) void attn_kernel(
    const float* __restrict__ messages,   // (B, NL, NN, P)
    const int*   __restrict__ adj,        // (B, NL, NN)
    const float* __restrict__ projx,      // (B, NN, P)
    const float* __restrict__ projy,
    const float* __restrict__ projz,
    const float* __restrict__ attn_w,     // (S, P)
    float* __restrict__ out)              // (B, S, NL, 3)
{
    int blk = blockIdx.x;        // b*NL + i
    int b = blk >> 7;
    int i = blk & (NL - 1);
    int t = threadIdx.x;
    int lane = t & 63;
    int wave = t >> 6;           // 0..7
    int pg = lane & 15;          // p-group: p = pg*4 .. pg*4+3
    int wsl = lane >> 4;         // 0..3
    int slice = wave * 4 + wsl;  // 0..31, n in [slice*12, slice*12+12)

    __shared__ float amask[NN];
    __shared__ float ls1[8][64], ls2[8][64];
    __shared__ float la0[8][64], la1[8][64], la2[8][64];
    __shared__ float upd[3][64];

    const int* adj_base = adj + (size_t)blk * NN;
    for (int n = t; n < NN; n += 512)
        amask[n] = adj_base[n] > 0 ? 0.f : -INFINITY;

    const float4* m4  = (const float4*)messages + (size_t)blk * NN * 16;
    const float4* px4 = (const float4*)projx + (size_t)b * NN * 16;
    const float4* py4 = (const float4*)projy + (size_t)b * NN * 16;
    const float4* pz4 = (const float4*)projz + (size_t)b * NN * 16;

    float4 xix = px4[(size_t)i * 16 + pg];
    float4 xiy = py4[(size_t)i * 16 + pg];
    float4 xiz = pz4[(size_t)i * 16 + pg];

    __syncthreads();

    float4 S1 = {0,0,0,0}, S2 = {0,0,0,0};
    float4 A0 = {0,0,0,0}, A1 = {0,0,0,0}, A2 = {0,0,0,0};

    int nb = slice * 12;
    size_t idx0 = (size_t)nb * 16 + pg;
    float4 mc = m4[idx0], xc = px4[idx0], yc = py4[idx0], zc = pz4[idx0];

    #pragma unroll
    for (int k = 0; k < 12; ++k) {
        int n = nb + k;
        float4 mm = mc, xx = xc, yy = yc, zz = zc;
        if (k < 11) {
            size_t idx = (size_t)(n + 1) * 16 + pg;
            mc = m4[idx]; xc = px4[idx]; yc = py4[idx]; zc = pz4[idx];
        }
        float am = amask[n];
        PROC(x) PROC(y) PROC(z) PROC(w)
    }

    // intra-wave reduce across the 4 n-subslices (lanes differing in bits 4,5)
    #pragma unroll
    for (int off = 16; off <= 32; off <<= 1) {
        RED(S1) RED(S2) RED(A0) RED(A1) RED(A2)
    }

    if (wsl == 0) {
        int pbase = pg * 4;
        ls1[wave][pbase+0] = S1.x; ls1[wave][pbase+1] = S1.y; ls1[wave][pbase+2] = S1.z; ls1[wave][pbase+3] = S1.w;
        ls2[wave][pbase+0] = S2.x; ls2[wave][pbase+1] = S2.y; ls2[wave][pbase+2] = S2.z; ls2[wave][pbase+3] = S2.w;
        la0[wave][pbase+0] = A0.x; la0[wave][pbase+1] = A0.y; la0[wave][pbase+2] = A0.z; la0[wave][pbase+3] = A0.w;
        la1[wave][pbase+0] = A1.x; la1[wave][pbase+1] = A1.y; la1[wave][pbase+2] = A1.z; la1[wave][pbase+3] = A1.w;
        la2[wave][pbase+0] = A2.x; la2[wave][pbase+1] = A2.y; la2[wave][pbase+2] = A2.z; la2[wave][pbase+3] = A2.w;
    }
    __syncthreads();

    if (t < 64) {
        float s1 = 0.f, s2 = 0.f, a0 = 0.f, a1 = 0.f, a2 = 0.f;
        #pragma unroll
        for (int w = 0; w < 8; ++w) {
            s1 += ls1[w][t]; s2 += ls2[w][t];
            a0 += la0[w][t]; a1 += la1[w][t]; a2 += la2[w][t];
        }
        // upd_final = (A/S1) * sqrt(S2)/S1
        float wgt = sqrtf(s2) / (s1 * s1);
        upd[0][t] = a0 * wgt;
        upd[1][t] = a1 * wgt;
        upd[2][t] = a2 * wgt;
    }
    __syncthreads();

    // out[b,s,i,c] = sum_p upd[c][p] * attn_w[s,p]; threads t<192: s=t&63, c=t>>6
    if (t < 192) {
        int s = t & 63, c = t >> 6;
        const float4* aw4 = (const float4*)attn_w + (size_t)s * 16;
        float o = 0.f;
        #pragma unroll
        for (int q = 0; q < 16; ++q) {
            float4 w4 = aw4[q];
            o = fmaf(upd[c][q*4+0], w4.x, o);
            o = fmaf(upd[c][q*4+1], w4.y, o);
            o = fmaf(upd[c][q*4+2], w4.z, o);
            o = fmaf(upd[c][q*4+3], w4.w, o);
        }
        out[(((size_t)b * S + s) * NL + i) * 3 + c] = o;
    }
}

extern "C" void kernel_launch(void* const* d_in, const int* in_sizes, int n_in,
                              void* d_out, int out_size, void* d_ws, size_t ws_size,
                              hipStream_t stream)
{
    const float* lig      = (const float*)d_in[0];   // (B,S,NL,3)
    const float* messages = (const float*)d_in[1];   // (B,NL,NN,P)
    const int*   adj      = (const int*)  d_in[2];   // (B,NL,NN)
    const float* ligmask  = (const float*)d_in[3];   // (B,S,NL)
    const float* pro      = (const float*)d_in[4];   // (B,S,NPRO,3)
    const float* promask  = (const float*)d_in[5];   // (B,S,NPRO)
    const float* ligw     = (const float*)d_in[6];   // (P,S)
    const float* prow     = (const float*)d_in[7];   // (P,S)
    const float* attnw    = (const float*)d_in[8];   // (S,P)
    const float* sw       = (const float*)d_in[9];   // (S,)
    float* out = (float*)d_out;

    const size_t plane = (size_t)B * NN * P;         // 196608 floats
    float* meanlen = (float*)d_ws;                               // 2 KB
    float* projx   = (float*)((char*)d_ws + 2048);
    float* projy   = projx + plane;
    float* projz   = projy + plane;

    meanlen_kernel<<<B * S, 64, 0, stream>>>(lig, ligmask, pro, promask, meanlen);
    proj_kernel<<<B * (NN / NGRP), 64, 0, stream>>>(lig, pro, ligmask, promask,
                                                    ligw, prow, sw, meanlen,
                                                    projx, projy, projz);
    attn_kernel<<<B * NL, 512, 0, stream>>>(messages, adj, projx, projy, projz,
                                            attnw, out);
}

// Round 4
// 52.884 us; speedup vs baseline: 1.0173x; 1.0173x over previous
//
#include <hip/hip_runtime.h>
#include <hip/hip_bf16.h>
#include <math.h>

#define B   8
#define S   64
#define NL  128
#define NPRO 256
#define NN  384   // NL + NPRO
#define P   64
#define NGRP 8
#define EPSF 1e-6f

// ---------------------------------------------------------------------------
// Kernel 1: mean_len[b,s]
// ---------------------------------------------------------------------------
__global__ __launch_bounds__(64) void meanlen_kernel(
    const float* __restrict__ lig, const float* __restrict__ ligmask,
    const float* __restrict__ pro, const float* __restrict__ promask,
    float* __restrict__ meanlen)
{
    int blk = blockIdx.x;              // b*S + s
    int t = threadIdx.x;
    float suml = 0.f, cnt = 0.f;

    const float* lbase = lig + (size_t)blk * NL * 3;
    const float* lm    = ligmask + (size_t)blk * NL;
    for (int n = t; n < NL; n += 64) {
        float x = lbase[n*3+0], y = lbase[n*3+1], z = lbase[n*3+2];
        float mk = lm[n];
        suml += sqrtf(x*x + y*y + z*z) * mk;
        cnt  += mk;
    }
    const float* pbase = pro + (size_t)blk * NPRO * 3;
    const float* pm    = promask + (size_t)blk * NPRO;
    for (int n = t; n < NPRO; n += 64) {
        float x = pbase[n*3+0], y = pbase[n*3+1], z = pbase[n*3+2];
        float mk = pm[n];
        suml += sqrtf(x*x + y*y + z*z) * mk;
        cnt  += mk;
    }
    for (int off = 32; off > 0; off >>= 1) {
        suml += __shfl_down(suml, off);
        cnt  += __shfl_down(cnt,  off);
    }
    if (t == 0) meanlen[blk] = suml / cnt;
}

// ---------------------------------------------------------------------------
// Kernel 2: SoA projection planes
// projc[b,n,p] = sum_s coord[b,s,n,c] * sw[s]/(mean+eps)*mask * w[p,s]
// ---------------------------------------------------------------------------
__global__ __launch_bounds__(64) void proj_kernel(
    const float* __restrict__ lig, const float* __restrict__ pro,
    const float* __restrict__ ligmask, const float* __restrict__ promask,
    const float* __restrict__ ligw, const float* __restrict__ prow,
    const float* __restrict__ sw, const float* __restrict__ meanlen,
    float* __restrict__ projx, float* __restrict__ projy, float* __restrict__ projz)
{
    int blk = blockIdx.x;
    int b = blk / (NN / NGRP);
    int g = blk - b * (NN / NGRP);
    int nbase = g * NGRP;
    int t = threadIdx.x;
    bool isl = (nbase < NL);

    __shared__ float wl[64][65];           // wl[p][s], padded
    const float* w = isl ? ligw : prow;    // (P,S)
    for (int row = 0; row < 64; ++row) wl[row][t] = w[row * 64 + t];

    __shared__ float cs[NGRP][3][64];      // coords premultiplied by g-factor
    {
        int s = t;
        float gfac = sw[s] / (meanlen[b * S + s] + EPSF);
        for (int nn = 0; nn < NGRP; ++nn) {
            int n = nbase + nn;
            float mk, X, Y, Z;
            if (isl) {
                size_t base = ((size_t)b * S + s) * NL + n;
                mk = ligmask[base];
                X = lig[base*3+0]; Y = lig[base*3+1]; Z = lig[base*3+2];
            } else {
                size_t base = ((size_t)b * S + s) * NPRO + (n - NL);
                mk = promask[base];
                X = pro[base*3+0]; Y = pro[base*3+1]; Z = pro[base*3+2];
            }
            float gg = gfac * mk;
            cs[nn][0][s] = X * gg;
            cs[nn][1][s] = Y * gg;
            cs[nn][2][s] = Z * gg;
        }
    }
    __syncthreads();

    for (int nn = 0; nn < NGRP; ++nn) {
        float a0 = 0.f, a1 = 0.f, a2 = 0.f;
        #pragma unroll 8
        for (int s = 0; s < 64; ++s) {
            float wv = wl[t][s];
            a0 += cs[nn][0][s] * wv;
            a1 += cs[nn][1][s] * wv;
            a2 += cs[nn][2][s] * wv;
        }
        size_t base = ((size_t)b * NN + nbase + nn) * P;
        projx[base + t] = a0;
        projy[base + t] = a1;
        projz[base + t] = a2;
    }
}

// ---------------------------------------------------------------------------
// Kernel 3 (dominant): i-PAIR version. Block = (b, ipair): two i rows share
// the proj loads and double per-thread ILP. grid = B*NL/2 = 512 blocks,
// 512 threads = 8 waves. Thread: pg = lane&15 (4 consecutive p),
// slice = wave*4 + (lane>>4) in [0,32) -> n in [slice*12, slice*12+12).
// Explicit 2-deep prefetch, fully unrolled (static buf[k&1] indexing).
// ---------------------------------------------------------------------------
#define PROC2(C) { \
    float d0 = xi0x.C - xx.C, d1 = xi0y.C - yy.C, d2 = xi0z.C - zz.C; \
    float sq = fmaf(d0, d0, fmaf(d1, d1, d2 * d2)); \
    float inv; asm("v_rsq_f32 %0, %1" : "=v"(inv) : "v"(sq)); \
    inv = fminf(inv, 1e30f); \
    float xe = fmaf(mm0.C, 1.44269504f, am0); \
    float e; asm("v_exp_f32 %0, %1" : "=v"(e) : "v"(xe)); \
    S1a.C += e; S2a.C = fmaf(e, e, S2a.C); \
    float ei = e * inv; \
    A0a.C = fmaf(ei, d0, A0a.C); A1a.C = fmaf(ei, d1, A1a.C); A2a.C = fmaf(ei, d2, A2a.C); \
    d0 = xi1x.C - xx.C; d1 = xi1y.C - yy.C; d2 = xi1z.C - zz.C; \
    sq = fmaf(d0, d0, fmaf(d1, d1, d2 * d2)); \
    asm("v_rsq_f32 %0, %1" : "=v"(inv) : "v"(sq)); \
    inv = fminf(inv, 1e30f); \
    xe = fmaf(mm1.C, 1.44269504f, am1); \
    asm("v_exp_f32 %0, %1" : "=v"(e) : "v"(xe)); \
    S1b.C += e; S2b.C = fmaf(e, e, S2b.C); \
    ei = e * inv; \
    A0b.C = fmaf(ei, d0, A0b.C); A1b.C = fmaf(ei, d1, A1b.C); A2b.C = fmaf(ei, d2, A2b.C); }

#define RED(V) { V.x += __shfl_xor(V.x, off); V.y += __shfl_xor(V.y, off); \
                 V.z += __shfl_xor(V.z, off); V.w += __shfl_xor(V.w, off); }

__global__ __launch_bounds__(512) void attn_kernel(
    const float* __restrict__ messages,   // (B, NL, NN, P)
    const int*   __restrict__ adj,        // (B, NL, NN)
    const float* __restrict__ projx,      // (B, NN, P)
    const float* __restrict__ projy,
    const float* __restrict__ projz,
    const float* __restrict__ attn_w,     // (S, P)
    float* __restrict__ out)              // (B, S, NL, 3)
{
    int blk = blockIdx.x;        // b*(NL/2) + ip
    int b = blk >> 6;
    int ip = blk & 63;
    int i0 = ip * 2;
    int i1 = i0 + 1;
    int t = threadIdx.x;
    int lane = t & 63;
    int wave = t >> 6;           // 0..7
    int pg = lane & 15;          // p-group: p = pg*4 .. pg*4+3
    int wsl = lane >> 4;         // 0..3
    int slice = wave * 4 + wsl;  // 0..31, n in [slice*12, slice*12+12)

    __shared__ float amask[2][NN];
    __shared__ __align__(16) float red[2][5][8][64];   // [i][acc][wave][p]
    __shared__ float upd[2][3][64];

    const int* adj0 = adj + ((size_t)b * NL + i0) * NN;
    const int* adj1 = adj + ((size_t)b * NL + i1) * NN;
    for (int n = t; n < NN; n += 512) {
        amask[0][n] = adj0[n] > 0 ? 0.f : -INFINITY;
        amask[1][n] = adj1[n] > 0 ? 0.f : -INFINITY;
    }

    const float4* m04 = (const float4*)messages + ((size_t)b * NL + i0) * NN * 16;
    const float4* m14 = (const float4*)messages + ((size_t)b * NL + i1) * NN * 16;
    const float4* px4 = (const float4*)projx + (size_t)b * NN * 16;
    const float4* py4 = (const float4*)projy + (size_t)b * NN * 16;
    const float4* pz4 = (const float4*)projz + (size_t)b * NN * 16;

    float4 xi0x = px4[(size_t)i0 * 16 + pg];
    float4 xi0y = py4[(size_t)i0 * 16 + pg];
    float4 xi0z = pz4[(size_t)i0 * 16 + pg];
    float4 xi1x = px4[(size_t)i1 * 16 + pg];
    float4 xi1y = py4[(size_t)i1 * 16 + pg];
    float4 xi1z = pz4[(size_t)i1 * 16 + pg];

    __syncthreads();

    float4 S1a = {0,0,0,0}, S2a = {0,0,0,0}, A0a = {0,0,0,0}, A1a = {0,0,0,0}, A2a = {0,0,0,0};
    float4 S1b = {0,0,0,0}, S2b = {0,0,0,0}, A0b = {0,0,0,0}, A1b = {0,0,0,0}, A2b = {0,0,0,0};

    int nb = slice * 12;
    size_t base = (size_t)nb * 16 + pg;

    float4 bm0[2], bm1[2], bx[2], by[2], bz[2];
    bm0[0] = m04[base];      bm1[0] = m14[base];
    bx[0]  = px4[base];      by[0]  = py4[base];      bz[0] = pz4[base];
    bm0[1] = m04[base + 16]; bm1[1] = m14[base + 16];
    bx[1]  = px4[base + 16]; by[1]  = py4[base + 16]; bz[1] = pz4[base + 16];

    #pragma unroll
    for (int k = 0; k < 12; ++k) {
        float4 mm0 = bm0[k & 1], mm1 = bm1[k & 1];
        float4 xx = bx[k & 1], yy = by[k & 1], zz = bz[k & 1];
        if (k < 10) {
            size_t idx = base + (size_t)(k + 2) * 16;
            bm0[k & 1] = m04[idx]; bm1[k & 1] = m14[idx];
            bx[k & 1]  = px4[idx]; by[k & 1]  = py4[idx]; bz[k & 1] = pz4[idx];
        }
        int n = nb + k;
        float am0 = amask[0][n], am1 = amask[1][n];
        PROC2(x) PROC2(y) PROC2(z) PROC2(w)
    }

    // intra-wave reduce across the 4 n-subslices (lane bits 4,5)
    #pragma unroll
    for (int off = 16; off <= 32; off <<= 1) {
        RED(S1a) RED(S2a) RED(A0a) RED(A1a) RED(A2a)
        RED(S1b) RED(S2b) RED(A0b) RED(A1b) RED(A2b)
    }

    if (wsl == 0) {
        int pb = pg * 4;
        *(float4*)&red[0][0][wave][pb] = S1a; *(float4*)&red[0][1][wave][pb] = S2a;
        *(float4*)&red[0][2][wave][pb] = A0a; *(float4*)&red[0][3][wave][pb] = A1a;
        *(float4*)&red[0][4][wave][pb] = A2a;
        *(float4*)&red[1][0][wave][pb] = S1b; *(float4*)&red[1][1][wave][pb] = S2b;
        *(float4*)&red[1][2][wave][pb] = A0b; *(float4*)&red[1][3][wave][pb] = A1b;
        *(float4*)&red[1][4][wave][pb] = A2b;
    }
    __syncthreads();

    if (t < 128) {
        int il = t >> 6, p = t & 63;
        float s1 = 0.f, s2 = 0.f, a0 = 0.f, a1 = 0.f, a2 = 0.f;
        #pragma unroll
        for (int w = 0; w < 8; ++w) {
            s1 += red[il][0][w][p]; s2 += red[il][1][w][p];
            a0 += red[il][2][w][p]; a1 += red[il][3][w][p]; a2 += red[il][4][w][p];
        }
        float wgt = sqrtf(s2) / (s1 * s1);   // (A/S1)*sqrt(S2)/S1
        upd[il][0][p] = a0 * wgt;
        upd[il][1][p] = a1 * wgt;
        upd[il][2][p] = a2 * wgt;
    }
    __syncthreads();

    // out[b,s,i,c] = sum_p upd[c][p] * attn_w[s,p]
    if (t < 384) {
        int il = t >= 192;
        int r = t - il * 192;
        int s = r & 63, c = r >> 6;
        int i = i0 + il;
        const float4* aw4 = (const float4*)attn_w + (size_t)s * 16;
        float o = 0.f;
        #pragma unroll
        for (int q = 0; q < 16; ++q) {
            float4 w4 = aw4[q];
            o = fmaf(upd[il][c][q*4+0], w4.x, o);
            o = fmaf(upd[il][c][q*4+1], w4.y, o);
            o = fmaf(upd[il][c][q*4+2], w4.z, o);
            o = fmaf(upd[il][c][q*4+3], w4.w, o);
        }
        out[(((size_t)b * S + s) * NL + i) * 3 + c] = o;
    }
}

extern "C" void kernel_launch(void* const* d_in, const int* in_sizes, int n_in,
                              void* d_out, int out_size, void* d_ws, size_t ws_size,
                              hipStream_t stream)
{
    const float* lig      = (const float*)d_in[0];   // (B,S,NL,3)
    const float* messages = (const float*)d_in[1];   // (B,NL,NN,P)
    const int*   adj      = (const int*)  d_in[2];   // (B,NL,NN)
    const float* ligmask  = (const float*)d_in[3];   // (B,S,NL)
    const float* pro      = (const float*)d_in[4];   // (B,S,NPRO,3)
    const float* promask  = (const float*)d_in[5];   // (B,S,NPRO)
    const float* ligw     = (const float*)d_in[6];   // (P,S)
    const float* prow     = (const float*)d_in[7];   // (P,S)
    const float* attnw    = (const float*)d_in[8];   // (S,P)
    const float* sw       = (const float*)d_in[9];   // (S,)
    float* out = (float*)d_out;

    const size_t plane = (size_t)B * NN * P;         // 196608 floats
    float* meanlen = (float*)d_ws;                               // 2 KB
    float* projx   = (float*)((char*)d_ws + 2048);
    float* projy   = projx + plane;
    float* projz   = projy + plane;

    meanlen_kernel<<<B * S, 64, 0, stream>>>(lig, ligmask, pro, promask, meanlen);
    proj_kernel<<<B * (NN / NGRP), 64, 0, stream>>>(lig, pro, ligmask, promask,
                                                    ligw, prow, sw, meanlen,
                                                    projx, projy, projz);
    attn_kernel<<<B * NL / 2, 512, 0, stream>>>(messages, adj, projx, projy, projz,
                                                attnw, out);
}